// Round 1
// baseline (3360.387 us; speedup 1.0000x reference)
//
#include <hip/hip_runtime.h>

#define TE 64   // edges/nodes per tile

// ---------------- setup kernels (run once per launch) ----------------

__global__ void hist_kernel(const int* __restrict__ ei, int* __restrict__ cnt, int E) {
  int e = blockIdx.x * blockDim.x + threadIdx.x;
  if (e < E) atomicAdd(&cnt[ei[E + e]], 1);
}

__global__ void bhist_kernel(const int* __restrict__ batch, int* __restrict__ gcnt, int N) {
  int n = blockIdx.x * blockDim.x + threadIdx.x;
  if (n < N) atomicAdd(&gcnt[batch[n]], 1);
}

// single-block exclusive scan of cnt[N] -> rctr[N], thread-coarsened x8
__global__ void scan_kernel(const int* __restrict__ cnt, int* __restrict__ rctr, int n) {
  __shared__ int sd[256];
  __shared__ int carry_s;
  const int tid = threadIdx.x;
  if (tid == 0) carry_s = 0;
  __syncthreads();
  for (int base = 0; base < n; base += 2048) {
    const int i0 = base + tid * 8;
    int v[8];
    int tot = 0;
#pragma unroll
    for (int j = 0; j < 8; ++j) {
      const int i = i0 + j;
      v[j] = (i < n) ? cnt[i] : 0;
      tot += v[j];
    }
    sd[tid] = tot;
    __syncthreads();
    for (int off = 1; off < 256; off <<= 1) {
      const int t = (tid >= off) ? sd[tid - off] : 0;
      __syncthreads();
      sd[tid] += t;
      __syncthreads();
    }
    int excl = sd[tid] - tot + carry_s;
#pragma unroll
    for (int j = 0; j < 8; ++j) {
      const int i = i0 + j;
      if (i < n) rctr[i] = excl;
      excl += v[j];
    }
    __syncthreads();                 // everyone has read carry_s
    if (tid == 255) carry_s += sd[255];
    __syncthreads();
  }
}

// counting-sort placement: sorted-by-col edge list (order within segment is
// nondeterministic; fp32 sum reorder noise ~1e-7, tolerance is 2% of absmax)
__global__ void place_kernel(const int* __restrict__ ei, int* __restrict__ rctr,
                             int* __restrict__ esrow, int* __restrict__ escol, int E) {
  int e = blockIdx.x * blockDim.x + threadIdx.x;
  if (e >= E) return;
  const int r = ei[e];
  const int c = ei[E + e];
  const int p = atomicAdd(&rctr[c], 1);
  esrow[p] = r;
  escol[p] = c;
}

// ---------------- edge MLP + fused segmented scatter-add ----------------
// m = relu(x[row] @ W1 + b1) @ W2 + b2 ; agg[col] += m  (sorted by col)
__global__ __launch_bounds__(128)
void edge_kernel(const float* __restrict__ x,
                 const int* __restrict__ esrow, const int* __restrict__ escol,
                 const float* __restrict__ W1, const float* __restrict__ b1,
                 const float* __restrict__ W2, const float* __restrict__ b2,
                 float* __restrict__ agg) {
  // one buffer reused sequentially: Xs[k][e] -> Hs[c1][e] -> Ms[e][c2]
  __shared__ __align__(16) float XHM[128 * TE];
  __shared__ __align__(16) float Ws[32 * 128];
  __shared__ int scol_s[TE];

  const int tid = threadIdx.x;
  const int e0 = blockIdx.x * TE;
  if (tid < TE) scol_s[tid] = escol[e0 + tid];

  // gather x rows -> Xs[k][e] (transposed for b128 reads along e)
  {
    const int e = tid >> 1;
    const int half = tid & 1;
    const int r = esrow[e0 + e];
    const float4* src = (const float4*)(x + (size_t)r * 128) + half * 16;
#pragma unroll
    for (int j = 0; j < 16; ++j) {
      const float4 v = src[j];
      const int c = half * 64 + j * 4;
      XHM[(c + 0) * TE + e] = v.x;
      XHM[(c + 1) * TE + e] = v.y;
      XHM[(c + 2) * TE + e] = v.z;
      XHM[(c + 3) * TE + e] = v.w;
    }
  }

  const int eg = (tid & 7) * 8;    // 8-edge group
  const int cg = (tid >> 3) * 8;   // 8-col group

  float acc[8][8];
#pragma unroll
  for (int i = 0; i < 8; ++i) {
#pragma unroll
    for (int j = 0; j < 8; ++j) acc[i][j] = 0.f;
  }

  // GEMM1: H1 = X @ W1   (K=128, 4 staged chunks of 32)
  for (int kc = 0; kc < 4; ++kc) {
    __syncthreads();
    {
      const float4* wsrc = (const float4*)(W1 + kc * 32 * 128);
#pragma unroll
      for (int j = 0; j < 8; ++j) ((float4*)Ws)[j * 128 + tid] = wsrc[j * 128 + tid];
    }
    __syncthreads();
#pragma unroll 8
    for (int k = 0; k < 32; ++k) {
      const int rowa = (kc * 32 + k) * TE;
      const float4 av0 = *(const float4*)&XHM[rowa + eg];
      const float4 av1 = *(const float4*)&XHM[rowa + eg + 4];
      const float4 bv0 = *(const float4*)&Ws[k * 128 + cg];
      const float4 bv1 = *(const float4*)&Ws[k * 128 + cg + 4];
      const float a[8] = {av0.x, av0.y, av0.z, av0.w, av1.x, av1.y, av1.z, av1.w};
      const float b[8] = {bv0.x, bv0.y, bv0.z, bv0.w, bv1.x, bv1.y, bv1.z, bv1.w};
#pragma unroll
      for (int i = 0; i < 8; ++i) {
#pragma unroll
        for (int j = 0; j < 8; ++j) acc[i][j] = fmaf(a[i], b[j], acc[i][j]);
      }
    }
  }

  // bias + relu -> Hs[c1][e] (overwrite Xs after barrier)
  __syncthreads();
  {
    const float4 ba = *(const float4*)(b1 + cg);
    const float4 bb = *(const float4*)(b1 + cg + 4);
    const float bias[8] = {ba.x, ba.y, ba.z, ba.w, bb.x, bb.y, bb.z, bb.w};
#pragma unroll
    for (int j = 0; j < 8; ++j) {
      float4 h0, h1;
      h0.x = fmaxf(acc[0][j] + bias[j], 0.f);
      h0.y = fmaxf(acc[1][j] + bias[j], 0.f);
      h0.z = fmaxf(acc[2][j] + bias[j], 0.f);
      h0.w = fmaxf(acc[3][j] + bias[j], 0.f);
      h1.x = fmaxf(acc[4][j] + bias[j], 0.f);
      h1.y = fmaxf(acc[5][j] + bias[j], 0.f);
      h1.z = fmaxf(acc[6][j] + bias[j], 0.f);
      h1.w = fmaxf(acc[7][j] + bias[j], 0.f);
      *(float4*)&XHM[(cg + j) * TE + eg] = h0;
      *(float4*)&XHM[(cg + j) * TE + eg + 4] = h1;
    }
  }

#pragma unroll
  for (int i = 0; i < 8; ++i) {
#pragma unroll
    for (int j = 0; j < 8; ++j) acc[i][j] = 0.f;
  }

  // GEMM2: M = H1 @ W2
  for (int kc = 0; kc < 4; ++kc) {
    __syncthreads();
    {
      const float4* wsrc = (const float4*)(W2 + kc * 32 * 128);
#pragma unroll
      for (int j = 0; j < 8; ++j) ((float4*)Ws)[j * 128 + tid] = wsrc[j * 128 + tid];
    }
    __syncthreads();
#pragma unroll 8
    for (int k = 0; k < 32; ++k) {
      const int rowa = (kc * 32 + k) * TE;
      const float4 av0 = *(const float4*)&XHM[rowa + eg];
      const float4 av1 = *(const float4*)&XHM[rowa + eg + 4];
      const float4 bv0 = *(const float4*)&Ws[k * 128 + cg];
      const float4 bv1 = *(const float4*)&Ws[k * 128 + cg + 4];
      const float a[8] = {av0.x, av0.y, av0.z, av0.w, av1.x, av1.y, av1.z, av1.w};
      const float b[8] = {bv0.x, bv0.y, bv0.z, bv0.w, bv1.x, bv1.y, bv1.z, bv1.w};
#pragma unroll
      for (int i = 0; i < 8; ++i) {
#pragma unroll
        for (int j = 0; j < 8; ++j) acc[i][j] = fmaf(a[i], b[j], acc[i][j]);
      }
    }
  }

  // +b2 -> Ms[e][c2] (overwrite Hs after barrier)
  __syncthreads();
  {
    const float4 ba = *(const float4*)(b2 + cg);
    const float4 bb = *(const float4*)(b2 + cg + 4);
#pragma unroll
    for (int i = 0; i < 8; ++i) {
      float4 m0, m1;
      m0.x = acc[i][0] + ba.x;  m0.y = acc[i][1] + ba.y;
      m0.z = acc[i][2] + ba.z;  m0.w = acc[i][3] + ba.w;
      m1.x = acc[i][4] + bb.x;  m1.y = acc[i][5] + bb.y;
      m1.z = acc[i][6] + bb.z;  m1.w = acc[i][7] + bb.w;
      *(float4*)&XHM[(eg + i) * 128 + cg] = m0;
      *(float4*)&XHM[(eg + i) * 128 + cg + 4] = m1;
    }
  }
  __syncthreads();

  // segmented reduce along sorted cols: ~1 atomic per distinct col per tile
  {
    const int c = tid;               // 128 threads = 128 feature cols
    int cur = scol_s[0];
    float s = 0.f;
    for (int e = 0; e < TE; ++e) {
      const int col = scol_s[e];     // wave-uniform broadcast
      const float v = XHM[e * 128 + c];
      if (col != cur) {
        atomicAdd(&agg[(size_t)cur * 128 + c], s);
        s = 0.f;
        cur = col;
      }
      s += v;
    }
    atomicAdd(&agg[(size_t)cur * 128 + c], s);
  }
}

// ---------------- node MLP (K=384 over 3 concat sources) ----------------
// x_new = relu([x, agg/cnt, u[batch]] @ W1 + b1) @ W2 + b2
__global__ __launch_bounds__(128)
void node_kernel(const float* __restrict__ xin, const float* __restrict__ agg,
                 const int* __restrict__ cnt, const float* __restrict__ u,
                 const int* __restrict__ batch,
                 const float* __restrict__ W1, const float* __restrict__ b1,
                 const float* __restrict__ W2, const float* __restrict__ b2,
                 float* __restrict__ xout, int N) {
  __shared__ __align__(16) float XH[128 * TE];
  __shared__ __align__(16) float Ws[32 * 128];

  const int tid = threadIdx.x;
  const int n0 = blockIdx.x * TE;
  const int eg = (tid & 7) * 8;
  const int cg = (tid >> 3) * 8;

  float acc[8][8];
#pragma unroll
  for (int i = 0; i < 8; ++i) {
#pragma unroll
    for (int j = 0; j < 8; ++j) acc[i][j] = 0.f;
  }

  for (int ph = 0; ph < 3; ++ph) {
    __syncthreads();  // previous phase's reads of XH are done
    {
      const int e = tid >> 1;
      const int half = tid & 1;
      int n = n0 + e;
      if (n > N - 1) n = N - 1;
      const float* srcp;
      float scale = 1.f;
      if (ph == 0) {
        srcp = xin + (size_t)n * 128;
      } else if (ph == 1) {
        srcp = agg + (size_t)n * 128;
        const int c_ = cnt[n];
        scale = 1.f / (float)(c_ > 1 ? c_ : 1);
      } else {
        srcp = u + (size_t)batch[n] * 128;
      }
      const float4* src = (const float4*)srcp + half * 16;
#pragma unroll
      for (int j = 0; j < 16; ++j) {
        const float4 v = src[j];
        const int c = half * 64 + j * 4;
        XH[(c + 0) * TE + e] = v.x * scale;
        XH[(c + 1) * TE + e] = v.y * scale;
        XH[(c + 2) * TE + e] = v.z * scale;
        XH[(c + 3) * TE + e] = v.w * scale;
      }
    }
    for (int kc = 0; kc < 4; ++kc) {
      __syncthreads();
      {
        const float4* wsrc = (const float4*)(W1 + (ph * 128 + kc * 32) * 128);
#pragma unroll
        for (int j = 0; j < 8; ++j) ((float4*)Ws)[j * 128 + tid] = wsrc[j * 128 + tid];
      }
      __syncthreads();
#pragma unroll 8
      for (int k = 0; k < 32; ++k) {
        const int rowa = (kc * 32 + k) * TE;
        const float4 av0 = *(const float4*)&XH[rowa + eg];
        const float4 av1 = *(const float4*)&XH[rowa + eg + 4];
        const float4 bv0 = *(const float4*)&Ws[k * 128 + cg];
        const float4 bv1 = *(const float4*)&Ws[k * 128 + cg + 4];
        const float a[8] = {av0.x, av0.y, av0.z, av0.w, av1.x, av1.y, av1.z, av1.w};
        const float b[8] = {bv0.x, bv0.y, bv0.z, bv0.w, bv1.x, bv1.y, bv1.z, bv1.w};
#pragma unroll
        for (int i = 0; i < 8; ++i) {
#pragma unroll
          for (int j = 0; j < 8; ++j) acc[i][j] = fmaf(a[i], b[j], acc[i][j]);
        }
      }
    }
  }

  // bias + relu -> Hs
  __syncthreads();
  {
    const float4 ba = *(const float4*)(b1 + cg);
    const float4 bb = *(const float4*)(b1 + cg + 4);
    const float bias[8] = {ba.x, ba.y, ba.z, ba.w, bb.x, bb.y, bb.z, bb.w};
#pragma unroll
    for (int j = 0; j < 8; ++j) {
      float4 h0, h1;
      h0.x = fmaxf(acc[0][j] + bias[j], 0.f);
      h0.y = fmaxf(acc[1][j] + bias[j], 0.f);
      h0.z = fmaxf(acc[2][j] + bias[j], 0.f);
      h0.w = fmaxf(acc[3][j] + bias[j], 0.f);
      h1.x = fmaxf(acc[4][j] + bias[j], 0.f);
      h1.y = fmaxf(acc[5][j] + bias[j], 0.f);
      h1.z = fmaxf(acc[6][j] + bias[j], 0.f);
      h1.w = fmaxf(acc[7][j] + bias[j], 0.f);
      *(float4*)&XH[(cg + j) * TE + eg] = h0;
      *(float4*)&XH[(cg + j) * TE + eg + 4] = h1;
    }
  }

#pragma unroll
  for (int i = 0; i < 8; ++i) {
#pragma unroll
    for (int j = 0; j < 8; ++j) acc[i][j] = 0.f;
  }

  // GEMM2
  for (int kc = 0; kc < 4; ++kc) {
    __syncthreads();
    {
      const float4* wsrc = (const float4*)(W2 + kc * 32 * 128);
#pragma unroll
      for (int j = 0; j < 8; ++j) ((float4*)Ws)[j * 128 + tid] = wsrc[j * 128 + tid];
    }
    __syncthreads();
#pragma unroll 8
    for (int k = 0; k < 32; ++k) {
      const int rowa = (kc * 32 + k) * TE;
      const float4 av0 = *(const float4*)&XH[rowa + eg];
      const float4 av1 = *(const float4*)&XH[rowa + eg + 4];
      const float4 bv0 = *(const float4*)&Ws[k * 128 + cg];
      const float4 bv1 = *(const float4*)&Ws[k * 128 + cg + 4];
      const float a[8] = {av0.x, av0.y, av0.z, av0.w, av1.x, av1.y, av1.z, av1.w};
      const float b[8] = {bv0.x, bv0.y, bv0.z, bv0.w, bv1.x, bv1.y, bv1.z, bv1.w};
#pragma unroll
      for (int i = 0; i < 8; ++i) {
#pragma unroll
        for (int j = 0; j < 8; ++j) acc[i][j] = fmaf(a[i], b[j], acc[i][j]);
      }
    }
  }

  // +b2, store to global
  {
    const float4 ba = *(const float4*)(b2 + cg);
    const float4 bb = *(const float4*)(b2 + cg + 4);
#pragma unroll
    for (int i = 0; i < 8; ++i) {
      const int n = n0 + eg + i;
      if (n < N) {
        float4 m0, m1;
        m0.x = acc[i][0] + ba.x;  m0.y = acc[i][1] + ba.y;
        m0.z = acc[i][2] + ba.z;  m0.w = acc[i][3] + ba.w;
        m1.x = acc[i][4] + bb.x;  m1.y = acc[i][5] + bb.y;
        m1.z = acc[i][6] + bb.z;  m1.w = acc[i][7] + bb.w;
        *(float4*)(xout + (size_t)n * 128 + cg) = m0;
        *(float4*)(xout + (size_t)n * 128 + cg + 4) = m1;
      }
    }
  }
}

// ---------------- global scatter-sum (batch is sorted) ----------------
__global__ __launch_bounds__(128)
void gsum_kernel(const float* __restrict__ xnew, const int* __restrict__ batch,
                 float* __restrict__ gx, int N) {
  const int tid = threadIdx.x;
  const int chunk = (N + gridDim.x - 1) / gridDim.x;
  const int n0 = blockIdx.x * chunk;
  int n1 = n0 + chunk;
  if (n1 > N) n1 = N;
  if (n0 >= N) return;
  int cur = batch[n0];
  float s = 0.f;
  for (int n = n0; n < n1; ++n) {
    const int b = batch[n];
    const float v = xnew[(size_t)n * 128 + tid];
    if (b != cur) {
      atomicAdd(&gx[(size_t)cur * 128 + tid], s);
      s = 0.f;
      cur = b;
    }
    s += v;
  }
  atomicAdd(&gx[(size_t)cur * 128 + tid], s);
}

// ---------------- global MLP: u_new = relu([u, gx/cnt]@gw1+gb1)@gw2+gb2 ----
__global__ __launch_bounds__(128)
void gmlp_kernel(const float* __restrict__ uin, const float* __restrict__ gx,
                 const int* __restrict__ gcnt,
                 const float* __restrict__ gw1, const float* __restrict__ gb1,
                 const float* __restrict__ gw2, const float* __restrict__ gb2,
                 float* __restrict__ uout) {
  __shared__ float g[256];
  __shared__ float g1[128];
  const int b = blockIdx.x;
  const int t = threadIdx.x;
  const int c = gcnt[b];
  const float inv = 1.f / (float)(c > 1 ? c : 1);
  g[t] = uin[b * 128 + t];
  g[128 + t] = gx[b * 128 + t] * inv;
  __syncthreads();
  float acc = gb1[t];
#pragma unroll 8
  for (int k = 0; k < 256; ++k) acc = fmaf(g[k], gw1[k * 128 + t], acc);
  g1[t] = fmaxf(acc, 0.f);
  __syncthreads();
  float acc2 = gb2[t];
#pragma unroll 8
  for (int k = 0; k < 128; ++k) acc2 = fmaf(g1[k], gw2[k * 128 + t], acc2);
  uout[b * 128 + t] = acc2;
}

// ---------------- host ----------------
extern "C" void kernel_launch(void* const* d_in, const int* in_sizes, int n_in,
                              void* d_out, int out_size, void* d_ws, size_t ws_size,
                              hipStream_t stream) {
  constexpr int N = 50000, E = 600000, B = 64, F = 128, L = 4;

  const float* x0    = (const float*)d_in[0];
  const int*   ei    = (const int*)  d_in[1];
  const float* u0    = (const float*)d_in[2];
  const int*   batch = (const int*)  d_in[3];
  const float* n1w1  = (const float*)d_in[4];
  const float* n1b1  = (const float*)d_in[5];
  const float* n1w2  = (const float*)d_in[6];
  const float* n1b2  = (const float*)d_in[7];
  const float* n2w1  = (const float*)d_in[8];
  const float* n2b1  = (const float*)d_in[9];
  const float* n2w2  = (const float*)d_in[10];
  const float* n2b2  = (const float*)d_in[11];
  const float* gw1   = (const float*)d_in[12];
  const float* gb1   = (const float*)d_in[13];
  const float* gw2   = (const float*)d_in[14];
  const float* gb2   = (const float*)d_in[15];
  float* out = (float*)d_out;

  // workspace carve (~57 MB), 256B-aligned slices
  char* p = (char*)d_ws;
  auto carve = [&](size_t bytes) -> void* {
    void* q = (void*)p;
    p += (bytes + 255) & ~(size_t)255;
    return q;
  };
  float* xbuf  = (float*)carve((size_t)N * F * 4);
  float* agg   = (float*)carve((size_t)N * F * 4);
  float* ubuf  = (float*)carve((size_t)B * F * 4);
  float* gx    = (float*)carve((size_t)B * F * 4);
  int*   cnt   = (int*)carve((size_t)N * 4);
  int*   rctr  = (int*)carve((size_t)N * 4);
  int*   gcnt  = (int*)carve((size_t)B * 4);
  int*   esrow = (int*)carve((size_t)E * 4);
  int*   escol = (int*)carve((size_t)E * 4);

  // build CSR-sorted edge list (edge_index reused by all 4 layers)
  hipMemsetAsync(cnt, 0, (size_t)N * 4, stream);
  hipMemsetAsync(gcnt, 0, (size_t)B * 4, stream);
  hist_kernel<<<(E + 255) / 256, 256, 0, stream>>>(ei, cnt, E);
  bhist_kernel<<<(N + 255) / 256, 256, 0, stream>>>(batch, gcnt, N);
  scan_kernel<<<1, 256, 0, stream>>>(cnt, rctr, N);
  place_kernel<<<(E + 255) / 256, 256, 0, stream>>>(ei, rctr, esrow, escol, E);

  for (int l = 0; l < L; ++l) {
    const float* xin  = l ? xbuf : x0;
    float*       xout = (l == L - 1) ? out : xbuf;
    const float* uin  = l ? ubuf : u0;
    float*       uout = (l == L - 1) ? out + (size_t)N * F : ubuf;

    hipMemsetAsync(agg, 0, (size_t)N * F * 4, stream);
    edge_kernel<<<E / TE, 128, 0, stream>>>(
        xin, esrow, escol,
        n1w1 + (size_t)l * 128 * 128, n1b1 + l * 128,
        n1w2 + (size_t)l * 128 * 128, n1b2 + l * 128, agg);
    node_kernel<<<(N + TE - 1) / TE, 128, 0, stream>>>(
        xin, agg, cnt, uin, batch,
        n2w1 + (size_t)l * 384 * 128, n2b1 + l * 128,
        n2w2 + (size_t)l * 128 * 128, n2b2 + l * 128, xout, N);
    hipMemsetAsync(gx, 0, (size_t)B * F * 4, stream);
    gsum_kernel<<<512, 128, 0, stream>>>(xout, batch, gx, N);
    gmlp_kernel<<<B, 128, 0, stream>>>(
        uin, gx, gcnt,
        gw1 + (size_t)l * 256 * 128, gb1 + l * 128,
        gw2 + (size_t)l * 128 * 128, gb2 + l * 128, uout);
  }
}

// Round 2
// 1694.419 us; speedup vs baseline: 1.9832x; 1.9832x over previous
//
#include <hip/hip_runtime.h>

typedef __bf16 bf16;
typedef bf16 bf16x8 __attribute__((ext_vector_type(8)));
typedef bf16 bf16x4 __attribute__((ext_vector_type(4)));
typedef float floatx4 __attribute__((ext_vector_type(4)));

#define MFMA __builtin_amdgcn_mfma_f32_16x16x32_bf16

// ---------------- setup kernels ----------------

__global__ void hist_kernel(const int* __restrict__ ei, int* __restrict__ cnt, int E) {
  int e = blockIdx.x * blockDim.x + threadIdx.x;
  if (e < E) atomicAdd(&cnt[ei[E + e]], 1);
}

__global__ void bhist_kernel(const int* __restrict__ batch, int* __restrict__ gcnt, int N) {
  int n = blockIdx.x * blockDim.x + threadIdx.x;
  if (n < N) atomicAdd(&gcnt[batch[n]], 1);
}

__global__ void scan_kernel(const int* __restrict__ cnt, int* __restrict__ rctr, int n) {
  __shared__ int sd[256];
  __shared__ int carry_s;
  const int tid = threadIdx.x;
  if (tid == 0) carry_s = 0;
  __syncthreads();
  for (int base = 0; base < n; base += 2048) {
    const int i0 = base + tid * 8;
    int v[8];
    int tot = 0;
#pragma unroll
    for (int j = 0; j < 8; ++j) {
      const int i = i0 + j;
      v[j] = (i < n) ? cnt[i] : 0;
      tot += v[j];
    }
    sd[tid] = tot;
    __syncthreads();
    for (int off = 1; off < 256; off <<= 1) {
      const int t = (tid >= off) ? sd[tid - off] : 0;
      __syncthreads();
      sd[tid] += t;
      __syncthreads();
    }
    int excl = sd[tid] - tot + carry_s;
#pragma unroll
    for (int j = 0; j < 8; ++j) {
      const int i = i0 + j;
      if (i < n) rctr[i] = excl;
      excl += v[j];
    }
    __syncthreads();
    if (tid == 255) carry_s += sd[255];
    __syncthreads();
  }
}

__global__ void place_kernel(const int* __restrict__ ei, int* __restrict__ rctr,
                             int* __restrict__ esrow, int* __restrict__ escol, int E) {
  int e = blockIdx.x * blockDim.x + threadIdx.x;
  if (e >= E) return;
  const int r = ei[e];
  const int c = ei[E + e];
  const int p = atomicAdd(&rctr[c], 1);
  esrow[p] = r;
  escol[p] = c;
}

// transpose+split: src [L][K][H] fp32 -> dst [L][2][H][K] bf16 (hi, lo)
__global__ void wsplit_kernel(const float* __restrict__ src, bf16* __restrict__ dst,
                              int K, int HH) {
  const int l = blockIdx.y;
  const int gid = blockIdx.x * blockDim.x + threadIdx.x;
  if (gid >= K * HH) return;
  const int h = gid / K, k = gid - h * K;
  const float v = src[(size_t)l * K * HH + (size_t)k * HH + h];
  const bf16 hi = (bf16)v;
  const bf16 lo = (bf16)(v - (float)hi);
  bf16* d = dst + (size_t)l * 2 * K * HH;
  d[(size_t)h * K + k] = hi;
  d[(size_t)K * HH + (size_t)h * K + k] = lo;
}

// x [n] fp32 -> xhi, xlo bf16
__global__ void xsplit_kernel(const float* __restrict__ x, bf16* __restrict__ xhi,
                              bf16* __restrict__ xlo, int n4) {
  const int i = blockIdx.x * 256 + threadIdx.x;
  if (i >= n4) return;
  const float4 v = ((const float4*)x)[i];
  bf16x4 h, l;
  const float vv[4] = {v.x, v.y, v.z, v.w};
#pragma unroll
  for (int r = 0; r < 4; ++r) {
    h[r] = (bf16)vv[r];
    l[r] = (bf16)(vv[r] - (float)h[r]);
  }
  *(bf16x4*)&xhi[(size_t)i * 4] = h;
  *(bf16x4*)&xlo[(size_t)i * 4] = l;
}

// ---------------- edge MLP (MFMA, split-bf16) + fused segmented scatter ----
// D1[h][e] = W1T x X  -> relu -> H1[e][h] hi/lo -> D2[f][e] = W2T x H1
// -> Ms[f][e] -> segmented col-sum -> atomicAdd agg
__global__ __launch_bounds__(256, 3)
void edge_mfma(const bf16* __restrict__ xhi, const bf16* __restrict__ xlo,
               const int* __restrict__ esrow, const int* __restrict__ escol,
               const bf16* __restrict__ w1t, const float* __restrict__ b1,
               const bf16* __restrict__ w2t, const float* __restrict__ b2,
               float* __restrict__ agg) {
  __shared__ __align__(16) bf16 H1[2][64 * 136];   // reused as Ms fp32 [128][65]
  __shared__ __align__(16) bf16 Xc[2][64 * 40];
  __shared__ int srow_s[64], scol_s[64];

  const int tid = threadIdx.x;
  const int e0 = blockIdx.x * 64;
  const int wave = tid >> 6, lane = tid & 63, q = lane >> 4, lr = lane & 15;
  const int hbase = wave * 32;

  if (tid < 64) {
    srow_s[tid] = esrow[e0 + tid];
    scol_s[tid] = escol[e0 + tid];
  }

  const floatx4 zz = {0.f, 0.f, 0.f, 0.f};
  floatx4 acc[2][4];
#pragma unroll
  for (int mt = 0; mt < 2; ++mt)
#pragma unroll
    for (int nt = 0; nt < 4; ++nt) acc[mt][nt] = zz;

  // ---- GEMM1: K=128 in 4 chunks of 32 ----
  for (int kc = 0; kc < 4; ++kc) {
    __syncthreads();
    {
      const int tt = tid & 127, e = tt >> 1, half = tt & 1;
      const int r = srow_s[e];
      const bf16* src = (tid < 128 ? xhi : xlo) + (size_t)r * 128 + kc * 32 + half * 16;
      const bf16x8 v0 = *(const bf16x8*)src;
      const bf16x8 v1 = *(const bf16x8*)(src + 8);
      bf16* dst = &Xc[tid < 128 ? 0 : 1][e * 40 + half * 16];
      *(bf16x8*)dst = v0;
      *(bf16x8*)(dst + 8) = v1;
    }
    __syncthreads();
    bf16x8 ah[2], al[2], bh[4], bl[4];
#pragma unroll
    for (int mt = 0; mt < 2; ++mt) {
      const bf16* wp = w1t + (size_t)(hbase + mt * 16 + lr) * 128 + kc * 32 + q * 8;
      ah[mt] = *(const bf16x8*)wp;
      al[mt] = *(const bf16x8*)(wp + 16384);
    }
#pragma unroll
    for (int nt = 0; nt < 4; ++nt) {
      const bf16* xp = &Xc[0][(nt * 16 + lr) * 40 + q * 8];
      bh[nt] = *(const bf16x8*)xp;
      bl[nt] = *(const bf16x8*)(xp + 64 * 40);
    }
#pragma unroll
    for (int nt = 0; nt < 4; ++nt)
#pragma unroll
      for (int mt = 0; mt < 2; ++mt) {
        acc[mt][nt] = MFMA(ah[mt], bh[nt], acc[mt][nt], 0, 0, 0);
        acc[mt][nt] = MFMA(al[mt], bh[nt], acc[mt][nt], 0, 0, 0);
        acc[mt][nt] = MFMA(ah[mt], bl[nt], acc[mt][nt], 0, 0, 0);
      }
  }

  // ---- epilogue 1: bias+relu, split, write H1[e][h] ----
#pragma unroll
  for (int mt = 0; mt < 2; ++mt) {
    const int h0 = hbase + mt * 16 + q * 4;
    const float* bp = &b1[h0];
#pragma unroll
    for (int nt = 0; nt < 4; ++nt) {
      const int e = nt * 16 + lr;
      bf16x4 hh, ll;
#pragma unroll
      for (int r = 0; r < 4; ++r) {
        const float v = fmaxf(acc[mt][nt][r] + bp[r], 0.f);
        hh[r] = (bf16)v;
        ll[r] = (bf16)(v - (float)hh[r]);
      }
      *(bf16x4*)&H1[0][e * 136 + h0] = hh;
      *(bf16x4*)&H1[1][e * 136 + h0] = ll;
      acc[mt][nt] = zz;
    }
  }
  __syncthreads();

  // ---- GEMM2: D2[f][e] = W2T x H1, K=128 ----
#pragma unroll
  for (int ks = 0; ks < 4; ++ks) {
    bf16x8 ah[2], al[2], bh[4], bl[4];
#pragma unroll
    for (int mt = 0; mt < 2; ++mt) {
      const bf16* wp = w2t + (size_t)(hbase + mt * 16 + lr) * 128 + ks * 32 + q * 8;
      ah[mt] = *(const bf16x8*)wp;
      al[mt] = *(const bf16x8*)(wp + 16384);
    }
#pragma unroll
    for (int nt = 0; nt < 4; ++nt) {
      const bf16* hp = &H1[0][(nt * 16 + lr) * 136 + ks * 32 + q * 8];
      bh[nt] = *(const bf16x8*)hp;
      bl[nt] = *(const bf16x8*)(hp + 64 * 136);
    }
#pragma unroll
    for (int nt = 0; nt < 4; ++nt)
#pragma unroll
      for (int mt = 0; mt < 2; ++mt) {
        acc[mt][nt] = MFMA(ah[mt], bh[nt], acc[mt][nt], 0, 0, 0);
        acc[mt][nt] = MFMA(al[mt], bh[nt], acc[mt][nt], 0, 0, 0);
        acc[mt][nt] = MFMA(ah[mt], bl[nt], acc[mt][nt], 0, 0, 0);
      }
  }
  __syncthreads();  // all H1 reads done; Ms overlays H1

  // ---- epilogue 2: +b2 -> Ms[f][e] fp32 ----
  float* Ms = (float*)&H1[0][0];
#pragma unroll
  for (int mt = 0; mt < 2; ++mt) {
    const int f0 = hbase + mt * 16 + q * 4;
    const float* bp = &b2[f0];
#pragma unroll
    for (int nt = 0; nt < 4; ++nt) {
      const int e = nt * 16 + lr;
#pragma unroll
      for (int r = 0; r < 4; ++r) Ms[(f0 + r) * 65 + e] = acc[mt][nt][r] + bp[r];
    }
  }
  __syncthreads();

  // ---- segmented reduce along sorted cols, one atomic per run ----
  {
    const int f = tid & 127;
    const int es = (tid >> 7) * 32;
    int cur = scol_s[es];
    float s = 0.f;
    for (int e = es; e < es + 32; ++e) {
      const int col = scol_s[e];
      const float v = Ms[f * 65 + e];
      if (col != cur) {
        atomicAdd(&agg[(size_t)cur * 128 + f], s);
        s = 0.f;
        cur = col;
      }
      s += v;
    }
    atomicAdd(&agg[(size_t)cur * 128 + f], s);
  }
}

// ---------------- node MLP (MFMA, split-bf16), K=384 concat ----------------
__global__ __launch_bounds__(256, 3)
void node_mfma(bf16* xh, bf16* xl,                       // in AND out (disjoint rows)
               const float* __restrict__ agg, const int* __restrict__ cnt,
               const float* __restrict__ u, const int* __restrict__ batch,
               const bf16* __restrict__ w1t, const float* __restrict__ b1,
               const bf16* __restrict__ w2t, const float* __restrict__ b2,
               float* __restrict__ xout, int N) {
  __shared__ __align__(16) bf16 H1[2][64 * 136];
  __shared__ __align__(16) bf16 Xc[2][64 * 40];

  const int tid = threadIdx.x;
  const int n0 = blockIdx.x * 64;
  const int wave = tid >> 6, lane = tid & 63, q = lane >> 4, lr = lane & 15;
  const int hbase = wave * 32;

  const floatx4 zz = {0.f, 0.f, 0.f, 0.f};
  floatx4 acc[2][4];
#pragma unroll
  for (int mt = 0; mt < 2; ++mt)
#pragma unroll
    for (int nt = 0; nt < 4; ++nt) acc[mt][nt] = zz;

  // ---- GEMM1: K=384 (x | agg/cnt | u[batch]) in 12 chunks ----
  for (int kc = 0; kc < 12; ++kc) {
    __syncthreads();
    {
      const int e = tid >> 2, part = tid & 3;
      int n = n0 + e;
      if (n > N - 1) n = N - 1;
      bf16x8 vh, vl;
      if (kc < 4) {
        vh = *(const bf16x8*)(xh + (size_t)n * 128 + kc * 32 + part * 8);
        vl = *(const bf16x8*)(xl + (size_t)n * 128 + kc * 32 + part * 8);
      } else {
        float vv[8];
        if (kc < 8) {
          const float* s = agg + (size_t)n * 128 + (kc - 4) * 32 + part * 8;
          const float4 a0 = *(const float4*)s;
          const float4 a1 = *(const float4*)(s + 4);
          const int c_ = cnt[n];
          const float inv = 1.f / (float)(c_ > 1 ? c_ : 1);
          vv[0] = a0.x * inv; vv[1] = a0.y * inv; vv[2] = a0.z * inv; vv[3] = a0.w * inv;
          vv[4] = a1.x * inv; vv[5] = a1.y * inv; vv[6] = a1.z * inv; vv[7] = a1.w * inv;
        } else {
          const float* s = u + (size_t)batch[n] * 128 + (kc - 8) * 32 + part * 8;
          const float4 a0 = *(const float4*)s;
          const float4 a1 = *(const float4*)(s + 4);
          vv[0] = a0.x; vv[1] = a0.y; vv[2] = a0.z; vv[3] = a0.w;
          vv[4] = a1.x; vv[5] = a1.y; vv[6] = a1.z; vv[7] = a1.w;
        }
#pragma unroll
        for (int r = 0; r < 8; ++r) {
          vh[r] = (bf16)vv[r];
          vl[r] = (bf16)(vv[r] - (float)vh[r]);
        }
      }
      *(bf16x8*)&Xc[0][e * 40 + part * 8] = vh;
      *(bf16x8*)&Xc[1][e * 40 + part * 8] = vl;
    }
    __syncthreads();
    bf16x8 ah[2], al[2], bh[4], bl[4];
#pragma unroll
    for (int mt = 0; mt < 2; ++mt) {
      const bf16* wp = w1t + (size_t)(hbase + mt * 16 + lr) * 384 + kc * 32 + q * 8;
      ah[mt] = *(const bf16x8*)wp;
      al[mt] = *(const bf16x8*)(wp + 49152);
    }
#pragma unroll
    for (int nt = 0; nt < 4; ++nt) {
      const bf16* xp = &Xc[0][(nt * 16 + lr) * 40 + q * 8];
      bh[nt] = *(const bf16x8*)xp;
      bl[nt] = *(const bf16x8*)(xp + 64 * 40);
    }
#pragma unroll
    for (int nt = 0; nt < 4; ++nt)
#pragma unroll
      for (int mt = 0; mt < 2; ++mt) {
        acc[mt][nt] = MFMA(ah[mt], bh[nt], acc[mt][nt], 0, 0, 0);
        acc[mt][nt] = MFMA(al[mt], bh[nt], acc[mt][nt], 0, 0, 0);
        acc[mt][nt] = MFMA(ah[mt], bl[nt], acc[mt][nt], 0, 0, 0);
      }
  }

  // ---- epilogue 1 ----
#pragma unroll
  for (int mt = 0; mt < 2; ++mt) {
    const int h0 = hbase + mt * 16 + q * 4;
    const float* bp = &b1[h0];
#pragma unroll
    for (int nt = 0; nt < 4; ++nt) {
      const int e = nt * 16 + lr;
      bf16x4 hh, ll;
#pragma unroll
      for (int r = 0; r < 4; ++r) {
        const float v = fmaxf(acc[mt][nt][r] + bp[r], 0.f);
        hh[r] = (bf16)v;
        ll[r] = (bf16)(v - (float)hh[r]);
      }
      *(bf16x4*)&H1[0][e * 136 + h0] = hh;
      *(bf16x4*)&H1[1][e * 136 + h0] = ll;
      acc[mt][nt] = zz;
    }
  }
  __syncthreads();

  // ---- GEMM2 ----
#pragma unroll
  for (int ks = 0; ks < 4; ++ks) {
    bf16x8 ah[2], al[2], bh[4], bl[4];
#pragma unroll
    for (int mt = 0; mt < 2; ++mt) {
      const bf16* wp = w2t + (size_t)(hbase + mt * 16 + lr) * 128 + ks * 32 + q * 8;
      ah[mt] = *(const bf16x8*)wp;
      al[mt] = *(const bf16x8*)(wp + 16384);
    }
#pragma unroll
    for (int nt = 0; nt < 4; ++nt) {
      const bf16* hp = &H1[0][(nt * 16 + lr) * 136 + ks * 32 + q * 8];
      bh[nt] = *(const bf16x8*)hp;
      bl[nt] = *(const bf16x8*)(hp + 64 * 136);
    }
#pragma unroll
    for (int nt = 0; nt < 4; ++nt)
#pragma unroll
      for (int mt = 0; mt < 2; ++mt) {
        acc[mt][nt] = MFMA(ah[mt], bh[nt], acc[mt][nt], 0, 0, 0);
        acc[mt][nt] = MFMA(al[mt], bh[nt], acc[mt][nt], 0, 0, 0);
        acc[mt][nt] = MFMA(ah[mt], bl[nt], acc[mt][nt], 0, 0, 0);
      }
  }

  // ---- epilogue 2: +b2, write xout fp32 + xh/xl bf16 (next layer) ----
#pragma unroll
  for (int mt = 0; mt < 2; ++mt) {
    const int f0 = hbase + mt * 16 + q * 4;
    const float* bp = &b2[f0];
#pragma unroll
    for (int nt = 0; nt < 4; ++nt) {
      const int n = n0 + nt * 16 + lr;
      if (n < N) {
        float vv[4];
        bf16x4 hh, ll;
#pragma unroll
        for (int r = 0; r < 4; ++r) {
          vv[r] = acc[mt][nt][r] + bp[r];
          hh[r] = (bf16)vv[r];
          ll[r] = (bf16)(vv[r] - (float)hh[r]);
        }
        float4 o;
        o.x = vv[0]; o.y = vv[1]; o.z = vv[2]; o.w = vv[3];
        *(float4*)&xout[(size_t)n * 128 + f0] = o;
        *(bf16x4*)&xh[(size_t)n * 128 + f0] = hh;
        *(bf16x4*)&xl[(size_t)n * 128 + f0] = ll;
      }
    }
  }
}

// ---------------- global scatter-sum (batch sorted) ----------------
__global__ __launch_bounds__(128)
void gsum_kernel(const float* __restrict__ xnew, const int* __restrict__ batch,
                 float* __restrict__ gx, int N) {
  const int tid = threadIdx.x;
  const int chunk = (N + gridDim.x - 1) / gridDim.x;
  const int n0 = blockIdx.x * chunk;
  int n1 = n0 + chunk;
  if (n1 > N) n1 = N;
  if (n0 >= N) return;
  int cur = batch[n0];
  float s = 0.f;
  for (int n = n0; n < n1; ++n) {
    const int b = batch[n];
    const float v = xnew[(size_t)n * 128 + tid];
    if (b != cur) {
      atomicAdd(&gx[(size_t)cur * 128 + tid], s);
      s = 0.f;
      cur = b;
    }
    s += v;
  }
  atomicAdd(&gx[(size_t)cur * 128 + tid], s);
}

// ---------------- global MLP ----------------
__global__ __launch_bounds__(128)
void gmlp_kernel(const float* __restrict__ uin, const float* __restrict__ gx,
                 const int* __restrict__ gcnt,
                 const float* __restrict__ gw1, const float* __restrict__ gb1,
                 const float* __restrict__ gw2, const float* __restrict__ gb2,
                 float* __restrict__ uout) {
  __shared__ float g[256];
  __shared__ float g1[128];
  const int b = blockIdx.x;
  const int t = threadIdx.x;
  const int c = gcnt[b];
  const float inv = 1.f / (float)(c > 1 ? c : 1);
  g[t] = uin[b * 128 + t];
  g[128 + t] = gx[b * 128 + t] * inv;
  __syncthreads();
  float acc = gb1[t];
#pragma unroll 8
  for (int k = 0; k < 256; ++k) acc = fmaf(g[k], gw1[k * 128 + t], acc);
  g1[t] = fmaxf(acc, 0.f);
  __syncthreads();
  float acc2 = gb2[t];
#pragma unroll 8
  for (int k = 0; k < 128; ++k) acc2 = fmaf(g1[k], gw2[k * 128 + t], acc2);
  uout[b * 128 + t] = acc2;
}

// ---------------- host ----------------
extern "C" void kernel_launch(void* const* d_in, const int* in_sizes, int n_in,
                              void* d_out, int out_size, void* d_ws, size_t ws_size,
                              hipStream_t stream) {
  constexpr int N = 50000, E = 600000, B = 64, F = 128, L = 4;

  const float* x0    = (const float*)d_in[0];
  const int*   ei    = (const int*)  d_in[1];
  const float* u0    = (const float*)d_in[2];
  const int*   batch = (const int*)  d_in[3];
  const float* n1w1  = (const float*)d_in[4];
  const float* n1b1  = (const float*)d_in[5];
  const float* n1w2  = (const float*)d_in[6];
  const float* n1b2  = (const float*)d_in[7];
  const float* n2w1  = (const float*)d_in[8];
  const float* n2b1  = (const float*)d_in[9];
  const float* n2w2  = (const float*)d_in[10];
  const float* n2b2  = (const float*)d_in[11];
  const float* gw1   = (const float*)d_in[12];
  const float* gb1   = (const float*)d_in[13];
  const float* gw2   = (const float*)d_in[14];
  const float* gb2   = (const float*)d_in[15];
  float* out = (float*)d_out;

  char* p = (char*)d_ws;
  auto carve = [&](size_t bytes) -> void* {
    void* q = (void*)p;
    p += (bytes + 255) & ~(size_t)255;
    return q;
  };
  float* xbuf  = (float*)carve((size_t)N * F * 4);
  float* agg   = (float*)carve((size_t)N * F * 4);
  float* ubuf  = (float*)carve((size_t)B * F * 4);
  float* gx    = (float*)carve((size_t)B * F * 4);
  int*   cnt   = (int*)carve((size_t)N * 4);
  int*   rctr  = (int*)carve((size_t)N * 4);
  int*   gcnt  = (int*)carve((size_t)B * 4);
  int*   esrow = (int*)carve((size_t)E * 4);
  int*   escol = (int*)carve((size_t)E * 4);
  bf16*  xhi   = (bf16*)carve((size_t)N * F * 2);
  bf16*  xlo   = (bf16*)carve((size_t)N * F * 2);
  bf16*  w1t_e = (bf16*)carve((size_t)L * 2 * 128 * 128 * 2);
  bf16*  w2t_e = (bf16*)carve((size_t)L * 2 * 128 * 128 * 2);
  bf16*  w1t_n = (bf16*)carve((size_t)L * 2 * 384 * 128 * 2);
  bf16*  w2t_n = (bf16*)carve((size_t)L * 2 * 128 * 128 * 2);

  // setup: CSR sort of edges + degree counts + split/transposed weights + split x
  hipMemsetAsync(cnt, 0, (size_t)N * 4, stream);
  hipMemsetAsync(gcnt, 0, (size_t)B * 4, stream);
  hist_kernel<<<(E + 255) / 256, 256, 0, stream>>>(ei, cnt, E);
  bhist_kernel<<<(N + 255) / 256, 256, 0, stream>>>(batch, gcnt, N);
  scan_kernel<<<1, 256, 0, stream>>>(cnt, rctr, N);
  place_kernel<<<(E + 255) / 256, 256, 0, stream>>>(ei, rctr, esrow, escol, E);
  wsplit_kernel<<<dim3(64, L), 256, 0, stream>>>(n1w1, w1t_e, 128, 128);
  wsplit_kernel<<<dim3(64, L), 256, 0, stream>>>(n1w2, w2t_e, 128, 128);
  wsplit_kernel<<<dim3(192, L), 256, 0, stream>>>(n2w1, w1t_n, 384, 128);
  wsplit_kernel<<<dim3(64, L), 256, 0, stream>>>(n2w2, w2t_n, 128, 128);
  xsplit_kernel<<<(N * F / 4 + 255) / 256, 256, 0, stream>>>(x0, xhi, xlo, N * F / 4);

  for (int l = 0; l < L; ++l) {
    float*       xout = (l == L - 1) ? out : xbuf;
    const float* uin  = l ? ubuf : u0;
    float*       uout = (l == L - 1) ? out + (size_t)N * F : ubuf;

    hipMemsetAsync(agg, 0, (size_t)N * F * 4, stream);
    edge_mfma<<<E / 64, 256, 0, stream>>>(
        xhi, xlo, esrow, escol,
        w1t_e + (size_t)l * 32768, n1b1 + l * 128,
        w2t_e + (size_t)l * 32768, n1b2 + l * 128, agg);
    node_mfma<<<(N + 63) / 64, 256, 0, stream>>>(
        xhi, xlo, agg, cnt, uin, batch,
        w1t_n + (size_t)l * 98304, n2b1 + l * 128,
        w2t_n + (size_t)l * 32768, n2b2 + l * 128, xout, N);
    hipMemsetAsync(gx, 0, (size_t)B * F * 4, stream);
    gsum_kernel<<<512, 128, 0, stream>>>(xout, batch, gx, N);
    gmlp_kernel<<<B, 128, 0, stream>>>(
        uin, gx, gcnt,
        gw1 + (size_t)l * 256 * 128, gb1 + l * 128,
        gw2 + (size_t)l * 128 * 128, gb2 + l * 128, uout);
  }
}